// Round 9
// baseline (380.410 us; speedup 1.0000x reference)
//
#include <hip/hip_runtime.h>

#define B_ 256
#define N_ 64
#define T_ 60
#define D_ 128
#define H_ 128

typedef __attribute__((ext_vector_type(8))) short short8;
typedef __attribute__((ext_vector_type(4))) float f32x4;

__device__ __forceinline__ unsigned short f2bf(float f) {
  unsigned int u = __builtin_bit_cast(unsigned int, f);
  u = u + 0x7FFFu + ((u >> 16) & 1u);   // round-to-nearest-even
  return (unsigned short)(u >> 16);
}

__device__ __forceinline__ float tanh_fast(float x) {
  float e = __builtin_amdgcn_exp2f(x * 2.885390081777927f);  // exp(2x)
  return 1.0f - 2.0f * __builtin_amdgcn_rcpf(e + 1.0f);
}

// LDS-only barrier: does not drain vmcnt, so in-flight global prefetch
// loads survive it.
__device__ __forceinline__ void lds_barrier() {
  asm volatile("s_waitcnt lgkmcnt(0)" ::: "memory");
  __builtin_amdgcn_s_barrier();
  asm volatile("" ::: "memory");
}

// Pack W (K=128 x N=128, row-major [k][n]) into bf16 B-fragment order:
// [kt(4)][nt(8)][lane(64)][elem(8)], value = W[kt*32 + 8*(l>>4) + i][nt*16 + (l&15)]
__global__ __launch_bounds__(256) void prep_weights(
    const float* __restrict__ sg_w1, const float* __restrict__ tg_w1,
    unsigned short* __restrict__ wfrag) {
  int tid = blockIdx.x * 256 + threadIdx.x;   // 0..4095
  if (tid >= 2 * 4 * 8 * 64) return;
  int l  = tid & 63;
  int nt = (tid >> 6) & 7;
  int kt = (tid >> 9) & 3;
  int m  = tid >> 11;
  const float* W = m ? tg_w1 : sg_w1;
  int n  = nt * 16 + (l & 15);
  int k0 = kt * 32 + 8 * (l >> 4);
  unsigned short* dst = wfrag + (size_t)tid * 8;
#pragma unroll
  for (int i = 0; i < 8; ++i) dst[i] = f2bf(W[(k0 + i) * H_ + n]);
}

// Block = (b, node-half). Streams x[b, nh*32 .. nh*32+31, :, :] as 32
// CONTIGUOUS 30KB slabs. NON-TEMPORAL x loads (read-once: bypass L2 alloc).
// Per slab: gate MLP, e=exp(gate) (bounded, no max), online accumulate
// acc[t][d] += e*x, den[t] += e in registers. 3 blocks/CU.
__global__ __launch_bounds__(256, 3) void spatial_kernel(
    const float* __restrict__ x,
    const unsigned short* __restrict__ wfrag_g,  // sg_w1 fragments
    const float* __restrict__ b1,
    const float* __restrict__ w2,
    float* __restrict__ acc_p,    // [512][64][128]
    float* __restrict__ den_p) {  // [512][64]
  __shared__ __align__(16) char tile[64 * 272];   // bf16 slab, 272B row stride
  __shared__ __align__(16) char wlds[32768];      // 32 B-fragments
  __shared__ float gpart[2][64];

  const int tid = threadIdx.x;
  const int bid = blockIdx.x;
  const int b  = bid >> 1;
  const int nh = bid & 1;

  const int sub = tid >> 5;    // 0..7   (row group)
  const int cg  = tid & 31;    // 0..31  (col group of 4 floats)

  const float* xb = x + (size_t)b * (N_ * T_ * D_) + (size_t)(nh * 32) * (T_ * D_);

  // per-thread row offsets within a slab (t clamped to 59: rows 60..63 are
  // padding whose outputs are never read)
  int roff[8];
#pragma unroll
  for (int r = 0; r < 8; ++r) {
    int t = 8 * r + sub;
    roff[r] = (t > 59 ? 59 : t) * D_ + 4 * cg;
  }

  const int l  = tid & 63;
  const int w  = tid >> 6;
  const int lg = l >> 4;
  const int lr = l & 15;
  const int wr = w >> 1;   // t-half  [32*wr, 32*wr+32)
  const int wc = w & 1;    // h-half  [64*wc, 64*wc+64)

  float b1v[4], w2v[4];
#pragma unroll
  for (int ntl = 0; ntl < 4; ++ntl) {
    b1v[ntl] = b1[wc * 64 + ntl * 16 + lr];
    w2v[ntl] = w2[wc * 64 + ntl * 16 + lr];
  }

  // ---- prologue: W-fragments -> LDS; issue slab-0 loads (non-temporal) ----
  float4 wtmp[8];
#pragma unroll
  for (int i = 0; i < 8; ++i)
    wtmp[i] = *(const float4*)(wfrag_g + (size_t)(tid + 256 * i) * 8);

  f32x4 pxA[8], pxB[8];
#pragma unroll
  for (int r = 0; r < 8; ++r)
    pxA[r] = __builtin_nontemporal_load((const f32x4*)(xb + roff[r]));

#pragma unroll
  for (int i = 0; i < 8; ++i)
    *(float4*)(wlds + (size_t)(tid + 256 * i) * 16) = wtmp[i];
  lds_barrier();

  f32x4 accr[8];
  float denr[8];
#pragma unroll
  for (int r = 0; r < 8; ++r) { accr[r] = (f32x4)(0.0f); denr[r] = 0.0f; }

#define SLAB_BODY(CUR, NXT, S)                                                  \
  {                                                                             \
    /* issue next slab's loads (fly under this slab's compute) */               \
    if ((S) < 31) {                                                             \
      const float* nsb = xb + (size_t)((S) + 1) * (T_ * D_);                    \
      _Pragma("unroll")                                                         \
      for (int r = 0; r < 8; ++r)                                               \
        NXT[r] = __builtin_nontemporal_load((const f32x4*)(nsb + roff[r]));     \
    }                                                                           \
    /* A: convert CUR -> bf16 tile */                                           \
    _Pragma("unroll")                                                           \
    for (int r = 0; r < 8; ++r) {                                               \
      const int t = 8 * r + sub;                                                \
      unsigned lo = ((unsigned)f2bf(CUR[r][1]) << 16) | f2bf(CUR[r][0]);        \
      unsigned hi = ((unsigned)f2bf(CUR[r][3]) << 16) | f2bf(CUR[r][2]);        \
      *(uint2*)(tile + t * 272 + cg * 8) = make_uint2(lo, hi);                  \
    }                                                                           \
    lds_barrier();                                                              \
    /* B: MFMA h = slab @ W1 (rows = t), gate partials */                       \
    {                                                                           \
      f32x4 macc[2][4];                                                         \
      _Pragma("unroll")                                                         \
      for (int mt = 0; mt < 2; ++mt)                                            \
        _Pragma("unroll")                                                       \
        for (int ntl = 0; ntl < 4; ++ntl) macc[mt][ntl] = (f32x4)(0.0f);        \
      _Pragma("unroll")                                                         \
      for (int kt = 0; kt < 4; ++kt) {                                          \
        _Pragma("unroll")                                                       \
        for (int mt = 0; mt < 2; ++mt) {                                        \
          const int row = 32 * wr + 16 * mt + lr;                               \
          short8 af = *(const short8*)(tile + row * 272 + kt * 64 + lg * 16);   \
          _Pragma("unroll")                                                     \
          for (int ntl = 0; ntl < 4; ++ntl) {                                   \
            short8 bf = *(const short8*)(                                       \
                wlds + ((kt * 8 + wc * 4 + ntl) * 64 + l) * 16);                \
            macc[mt][ntl] = __builtin_amdgcn_mfma_f32_16x16x32_bf16(            \
                af, bf, macc[mt][ntl], 0, 0, 0);                                \
          }                                                                     \
        }                                                                       \
      }                                                                         \
      _Pragma("unroll")                                                         \
      for (int mt = 0; mt < 2; ++mt) {                                          \
        _Pragma("unroll")                                                       \
        for (int j = 0; j < 4; ++j) {                                           \
          float sg = 0.f;                                                       \
          _Pragma("unroll")                                                     \
          for (int ntl = 0; ntl < 4; ++ntl) {                                   \
            float h = macc[mt][ntl][j] + b1v[ntl];                              \
            sg += tanh_fast(h) * w2v[ntl];                                      \
          }                                                                     \
          sg += __shfl_xor(sg, 1);                                              \
          sg += __shfl_xor(sg, 2);                                              \
          sg += __shfl_xor(sg, 4);                                              \
          sg += __shfl_xor(sg, 8);                                              \
          if (lr == 0) gpart[wc][32 * wr + 16 * mt + 4 * lg + j] = sg;          \
        }                                                                       \
      }                                                                         \
    }                                                                           \
    lds_barrier();                                                              \
    /* D: e = exp(gate), online accumulate from CUR registers */                \
    _Pragma("unroll")                                                           \
    for (int r = 0; r < 8; ++r) {                                               \
      const int t = 8 * r + sub;                                                \
      float g = gpart[0][t] + gpart[1][t];                                      \
      float e = __builtin_amdgcn_exp2f(g * 1.4426950408889634f);                \
      accr[r][0] += e * CUR[r][0];                                              \
      accr[r][1] += e * CUR[r][1];                                              \
      accr[r][2] += e * CUR[r][2];                                              \
      accr[r][3] += e * CUR[r][3];                                              \
      denr[r] += e;                                                             \
    }                                                                           \
    lds_barrier();                                                              \
  }

  for (int sp = 0; sp < 16; ++sp) {
    const int s0 = 2 * sp;
    SLAB_BODY(pxA, pxB, s0);
    SLAB_BODY(pxB, pxA, s0 + 1);
  }
#undef SLAB_BODY

  // ---- epilogue: write partial acc / den ----
#pragma unroll
  for (int r = 0; r < 8; ++r) {
    const int t = 8 * r + sub;
    *(f32x4*)(acc_p + ((size_t)bid * 64 + t) * D_ + 4 * cg) = accr[r];
  }
  if (cg == 0) {
#pragma unroll
    for (int r = 0; r < 8; ++r) den_p[bid * 64 + 8 * r + sub] = denr[r];
  }
}

__global__ __launch_bounds__(256) void temporal_kernel(
    const float* __restrict__ acc_p,
    const float* __restrict__ den_p,
    const short8* __restrict__ wfrag,     // fragments of tg_w1
    const float* __restrict__ b1,
    const float* __restrict__ w2,
    float* __restrict__ out) {
  __shared__ float xs[64][132];
  __shared__ float score_lds[64];
  __shared__ float tw_lds[64];
  __shared__ float pp[2][128];

  const int tid = threadIdx.x;
  const int b = blockIdx.x;

  // combine the two node-half partials into pooled rows on load
  const float* a0 = acc_p + (size_t)(2 * b) * (64 * D_);
  const float* a1 = a0 + 64 * D_;
  const float* d0 = den_p + (2 * b) * 64;
  const float* d1 = d0 + 64;
#pragma unroll
  for (int it = 0; it < 8; ++it) {
    int q = it * 256 + tid;
    int n = q >> 5;
    int c4 = (q & 31) << 2;
    float4 v = {0.f, 0.f, 0.f, 0.f};
    if (n < T_) {
      float4 v0 = *(const float4*)(a0 + n * D_ + c4);
      float4 v1 = *(const float4*)(a1 + n * D_ + c4);
      float inv = __builtin_amdgcn_rcpf(d0[n] + d1[n]);
      v.x = (v0.x + v1.x) * inv;
      v.y = (v0.y + v1.y) * inv;
      v.z = (v0.z + v1.z) * inv;
      v.w = (v0.w + v1.w) * inv;
    }
    *(float4*)(&xs[n][c4]) = v;   // rows 60..63 zero-padded
  }
  __syncthreads();

  const int l = tid & 63;
  const int w = tid >> 6;
  const int lg = l >> 4;
  const int lr = l & 15;

  float b1v[8], w2v[8];
#pragma unroll
  for (int nt = 0; nt < 8; ++nt) {
    b1v[nt] = b1[nt * 16 + lr];
    w2v[nt] = w2[nt * 16 + lr];
  }

  f32x4 acc[8];
#pragma unroll
  for (int nt = 0; nt < 8; ++nt) acc[nt] = (f32x4)(0.0f);

  const int row = 16 * w + lr;
#pragma unroll
  for (int kt = 0; kt < 4; ++kt) {
    const int k0 = kt * 32 + 8 * lg;
    float4 a0v = *(const float4*)(&xs[row][k0]);
    float4 a1v = *(const float4*)(&xs[row][k0 + 4]);
    short8 af;
    af[0] = (short)f2bf(a0v.x); af[1] = (short)f2bf(a0v.y);
    af[2] = (short)f2bf(a0v.z); af[3] = (short)f2bf(a0v.w);
    af[4] = (short)f2bf(a1v.x); af[5] = (short)f2bf(a1v.y);
    af[6] = (short)f2bf(a1v.z); af[7] = (short)f2bf(a1v.w);
#pragma unroll
    for (int nt = 0; nt < 8; ++nt) {
      short8 bf = wfrag[(kt * 8 + nt) * 64 + l];
      acc[nt] = __builtin_amdgcn_mfma_f32_16x16x32_bf16(af, bf, acc[nt], 0, 0, 0);
    }
  }

#pragma unroll
  for (int j = 0; j < 4; ++j) {
    float s = 0.f;
#pragma unroll
    for (int nt = 0; nt < 8; ++nt) {
      float h = acc[nt][j] + b1v[nt];
      s += tanh_fast(h) * w2v[nt];
    }
    s += __shfl_xor(s, 1);
    s += __shfl_xor(s, 2);
    s += __shfl_xor(s, 4);
    s += __shfl_xor(s, 8);
    if (lr == 0) score_lds[16 * w + 4 * lg + j] = s;
  }
  __syncthreads();

  // masked softmax over T=60 (no max shift; scores bounded)
  float p = (l < T_) ? __builtin_amdgcn_exp2f(score_lds[l] * 1.4426950408889634f) : 0.f;
  float sm = p;
  sm += __shfl_xor(sm, 32);
  sm += __shfl_xor(sm, 16);
  sm += __shfl_xor(sm, 8);
  sm += __shfl_xor(sm, 4);
  sm += __shfl_xor(sm, 2);
  sm += __shfl_xor(sm, 1);
  float tw = p / sm;
  if (w == 0) {
    tw_lds[l] = tw;
    if (l < T_) out[B_ * D_ + b * T_ + l] = tw;   // tw output
  }
  __syncthreads();

  const int c = tid & 127;
  const int hh = tid >> 7;
  float s = 0.f;
#pragma unroll
  for (int i = 0; i < 30; ++i) {
    int tt = 30 * hh + i;
    s += tw_lds[tt] * xs[tt][c];
  }
  pp[hh][c] = s;
  __syncthreads();
  if (tid < 128) out[(size_t)b * D_ + tid] = pp[0][tid] + pp[1][tid];
}

extern "C" void kernel_launch(void* const* d_in, const int* in_sizes, int n_in,
                              void* d_out, int out_size, void* d_ws, size_t ws_size,
                              hipStream_t stream) {
  const float* x     = (const float*)d_in[0];
  const float* sg_w1 = (const float*)d_in[1];
  const float* sg_b1 = (const float*)d_in[2];
  const float* sg_w2 = (const float*)d_in[3];
  const float* tg_w1 = (const float*)d_in[5];
  const float* tg_b1 = (const float*)d_in[6];
  const float* tg_w2 = (const float*)d_in[7];
  float* out = (float*)d_out;

  unsigned short* wfrag = (unsigned short*)d_ws;            // 64 KB (sg @0, tg @16384)
  float* acc_p = (float*)((char*)d_ws + 65536);             // 512*64*128 f32 = 16.8 MB
  float* den_p = (float*)((char*)d_ws + 65536 + 16777216);  // 512*64 f32

  prep_weights<<<16, 256, 0, stream>>>(sg_w1, tg_w1, wfrag);
  spatial_kernel<<<B_ * 2, 256, 0, stream>>>(
      x, wfrag, sg_b1, sg_w2, acc_p, den_p);
  temporal_kernel<<<B_, 256, 0, stream>>>(
      acc_p, den_p, (const short8*)(wfrag + 16384), tg_b1, tg_w2, out);
}

// Round 10
// 145.329 us; speedup vs baseline: 2.6176x; 2.6176x over previous
//
#include <hip/hip_runtime.h>

#define B_ 256
#define N_ 64
#define T_ 60
#define D_ 128
#define H_ 128

typedef __attribute__((ext_vector_type(8))) short short8;
typedef __attribute__((ext_vector_type(4))) float f32x4;

__device__ __forceinline__ unsigned short f2bf(float f) {
  unsigned int u = __builtin_bit_cast(unsigned int, f);
  u = u + 0x7FFFu + ((u >> 16) & 1u);   // round-to-nearest-even
  return (unsigned short)(u >> 16);
}

__device__ __forceinline__ float tanh_fast(float x) {
  float e = __builtin_amdgcn_exp2f(x * 2.885390081777927f);  // exp(2x)
  return 1.0f - 2.0f * __builtin_amdgcn_rcpf(e + 1.0f);
}

// LDS-only barrier: does not drain vmcnt, so in-flight global prefetch
// loads survive it.
__device__ __forceinline__ void lds_barrier() {
  asm volatile("s_waitcnt lgkmcnt(0)" ::: "memory");
  __builtin_amdgcn_s_barrier();
  asm volatile("" ::: "memory");
}

// Pack W (K=128 x N=128, row-major [k][n]) into bf16 B-fragment order:
// [kt(4)][nt(8)][lane(64)][elem(8)], value = W[kt*32 + 8*(l>>4) + i][nt*16 + (l&15)]
__global__ __launch_bounds__(256) void prep_weights(
    const float* __restrict__ sg_w1, const float* __restrict__ tg_w1,
    unsigned short* __restrict__ wfrag) {
  int tid = blockIdx.x * 256 + threadIdx.x;   // 0..4095
  if (tid >= 2 * 4 * 8 * 64) return;
  int l  = tid & 63;
  int nt = (tid >> 6) & 7;
  int kt = (tid >> 9) & 3;
  int m  = tid >> 11;
  const float* W = m ? tg_w1 : sg_w1;
  int n  = nt * 16 + (l & 15);
  int k0 = kt * 32 + 8 * (l >> 4);
  unsigned short* dst = wfrag + (size_t)tid * 8;
#pragma unroll
  for (int i = 0; i < 8; ++i) dst[i] = f2bf(W[(k0 + i) * H_ + n]);
}

// Block = (b, node-half). Streams x[b, nh*32 .. nh*32+31, :, :] as 32
// CONTIGUOUS 30KB slabs (block footprint = one linear ~1MB sweep).
// Per slab: gate MLP over rows t (M=64 pad), e=exp(gate) (bounded, no max),
// online-accumulate acc[t][d] += e*x and den[t] += e in REGISTERS.
// W fragments live in LDS (keeps vmcnt queue = px prefetch only).
// NOTE: (256,2) launch bound is load-bearing — (256,3) spilled the px
// double-buffer to scratch (R9: VGPR 84, 2.5x regression).
__global__ __launch_bounds__(256, 2) void spatial_kernel(
    const float* __restrict__ x,
    const unsigned short* __restrict__ wfrag_g,  // sg_w1 fragments
    const float* __restrict__ b1,
    const float* __restrict__ w2,
    float* __restrict__ acc_p,    // [512][64][128]
    float* __restrict__ den_p) {  // [512][64]
  __shared__ __align__(16) char tile[64 * 272];   // bf16 slab, 272B row stride
  __shared__ __align__(16) char wlds[32768];      // 32 B-fragments
  __shared__ float gpart[2][64];

  const int tid = threadIdx.x;
  const int bid = blockIdx.x;
  const int b  = bid >> 1;
  const int nh = bid & 1;

  const int sub = tid >> 5;    // 0..7   (row group)
  const int cg  = tid & 31;    // 0..31  (col group of 4 floats)

  const float* xb = x + (size_t)b * (N_ * T_ * D_) + (size_t)(nh * 32) * (T_ * D_);

  // per-thread row offsets within a slab (t clamped to 59: rows 60..63 are
  // padding whose outputs are never read)
  int roff[8];
#pragma unroll
  for (int r = 0; r < 8; ++r) {
    int t = 8 * r + sub;
    roff[r] = (t > 59 ? 59 : t) * D_ + 4 * cg;
  }

  const int l  = tid & 63;
  const int w  = tid >> 6;
  const int lg = l >> 4;
  const int lr = l & 15;
  const int wr = w >> 1;   // t-half  [32*wr, 32*wr+32)
  const int wc = w & 1;    // h-half  [64*wc, 64*wc+64)

  float b1v[4], w2v[4];
#pragma unroll
  for (int ntl = 0; ntl < 4; ++ntl) {
    b1v[ntl] = b1[wc * 64 + ntl * 16 + lr];
    w2v[ntl] = w2[wc * 64 + ntl * 16 + lr];
  }

  // ---- prologue: W-fragments -> LDS; issue slab-0 loads ----
  float4 wtmp[8];
#pragma unroll
  for (int i = 0; i < 8; ++i)
    wtmp[i] = *(const float4*)(wfrag_g + (size_t)(tid + 256 * i) * 8);

  float4 pxA[8], pxB[8];
#pragma unroll
  for (int r = 0; r < 8; ++r) pxA[r] = *(const float4*)(xb + roff[r]);

#pragma unroll
  for (int i = 0; i < 8; ++i)
    *(float4*)(wlds + (size_t)(tid + 256 * i) * 16) = wtmp[i];
  lds_barrier();

  f32x4 accr[8];
  float denr[8];
#pragma unroll
  for (int r = 0; r < 8; ++r) { accr[r] = (f32x4)(0.0f); denr[r] = 0.0f; }

#define SLAB_BODY(CUR, NXT, S)                                                  \
  {                                                                             \
    /* issue next slab's loads (fly under this slab's compute) */               \
    if ((S) < 31) {                                                             \
      const float* nsb = xb + (size_t)((S) + 1) * (T_ * D_);                    \
      _Pragma("unroll")                                                         \
      for (int r = 0; r < 8; ++r) NXT[r] = *(const float4*)(nsb + roff[r]);     \
    }                                                                           \
    /* A: convert CUR -> bf16 tile */                                           \
    _Pragma("unroll")                                                           \
    for (int r = 0; r < 8; ++r) {                                               \
      const int t = 8 * r + sub;                                                \
      unsigned lo = ((unsigned)f2bf(CUR[r].y) << 16) | f2bf(CUR[r].x);          \
      unsigned hi = ((unsigned)f2bf(CUR[r].w) << 16) | f2bf(CUR[r].z);          \
      *(uint2*)(tile + t * 272 + cg * 8) = make_uint2(lo, hi);                  \
    }                                                                           \
    lds_barrier();                                                              \
    /* B: MFMA h = slab @ W1 (rows = t), gate partials */                       \
    {                                                                           \
      f32x4 macc[2][4];                                                         \
      _Pragma("unroll")                                                         \
      for (int mt = 0; mt < 2; ++mt)                                            \
        _Pragma("unroll")                                                       \
        for (int ntl = 0; ntl < 4; ++ntl) macc[mt][ntl] = (f32x4)(0.0f);        \
      _Pragma("unroll")                                                         \
      for (int kt = 0; kt < 4; ++kt) {                                          \
        _Pragma("unroll")                                                       \
        for (int mt = 0; mt < 2; ++mt) {                                        \
          const int row = 32 * wr + 16 * mt + lr;                               \
          short8 af = *(const short8*)(tile + row * 272 + kt * 64 + lg * 16);   \
          _Pragma("unroll")                                                     \
          for (int ntl = 0; ntl < 4; ++ntl) {                                   \
            short8 bf = *(const short8*)(                                       \
                wlds + ((kt * 8 + wc * 4 + ntl) * 64 + l) * 16);                \
            macc[mt][ntl] = __builtin_amdgcn_mfma_f32_16x16x32_bf16(            \
                af, bf, macc[mt][ntl], 0, 0, 0);                                \
          }                                                                     \
        }                                                                       \
      }                                                                         \
      _Pragma("unroll")                                                         \
      for (int mt = 0; mt < 2; ++mt) {                                          \
        _Pragma("unroll")                                                       \
        for (int j = 0; j < 4; ++j) {                                           \
          float sg = 0.f;                                                       \
          _Pragma("unroll")                                                     \
          for (int ntl = 0; ntl < 4; ++ntl) {                                   \
            float h = macc[mt][ntl][j] + b1v[ntl];                              \
            sg += tanh_fast(h) * w2v[ntl];                                      \
          }                                                                     \
          sg += __shfl_xor(sg, 1);                                              \
          sg += __shfl_xor(sg, 2);                                              \
          sg += __shfl_xor(sg, 4);                                              \
          sg += __shfl_xor(sg, 8);                                              \
          if (lr == 0) gpart[wc][32 * wr + 16 * mt + 4 * lg + j] = sg;          \
        }                                                                       \
      }                                                                         \
    }                                                                           \
    lds_barrier();                                                              \
    /* D: e = exp(gate), online accumulate from CUR registers */                \
    _Pragma("unroll")                                                           \
    for (int r = 0; r < 8; ++r) {                                               \
      const int t = 8 * r + sub;                                                \
      float g = gpart[0][t] + gpart[1][t];                                      \
      float e = __builtin_amdgcn_exp2f(g * 1.4426950408889634f);                \
      accr[r][0] += e * CUR[r].x;                                               \
      accr[r][1] += e * CUR[r].y;                                               \
      accr[r][2] += e * CUR[r].z;                                               \
      accr[r][3] += e * CUR[r].w;                                               \
      denr[r] += e;                                                             \
    }                                                                           \
    lds_barrier();                                                              \
  }

  for (int sp = 0; sp < 16; ++sp) {
    const int s0 = 2 * sp;
    SLAB_BODY(pxA, pxB, s0);
    SLAB_BODY(pxB, pxA, s0 + 1);
  }
#undef SLAB_BODY

  // ---- epilogue: write partial acc / den ----
#pragma unroll
  for (int r = 0; r < 8; ++r) {
    const int t = 8 * r + sub;
    *(f32x4*)(acc_p + ((size_t)bid * 64 + t) * D_ + 4 * cg) = accr[r];
  }
  if (cg == 0) {
#pragma unroll
    for (int r = 0; r < 8; ++r) den_p[bid * 64 + 8 * r + sub] = denr[r];
  }
}

__global__ __launch_bounds__(256) void temporal_kernel(
    const float* __restrict__ acc_p,
    const float* __restrict__ den_p,
    const short8* __restrict__ wfrag,     // fragments of tg_w1
    const float* __restrict__ b1,
    const float* __restrict__ w2,
    float* __restrict__ out) {
  __shared__ float xs[64][132];
  __shared__ float score_lds[64];
  __shared__ float tw_lds[64];
  __shared__ float pp[2][128];

  const int tid = threadIdx.x;
  const int b = blockIdx.x;

  // combine the two node-half partials into pooled rows on load
  const float* a0 = acc_p + (size_t)(2 * b) * (64 * D_);
  const float* a1 = a0 + 64 * D_;
  const float* d0 = den_p + (2 * b) * 64;
  const float* d1 = d0 + 64;
#pragma unroll
  for (int it = 0; it < 8; ++it) {
    int q = it * 256 + tid;
    int n = q >> 5;
    int c4 = (q & 31) << 2;
    float4 v = {0.f, 0.f, 0.f, 0.f};
    if (n < T_) {
      float4 v0 = *(const float4*)(a0 + n * D_ + c4);
      float4 v1 = *(const float4*)(a1 + n * D_ + c4);
      float inv = __builtin_amdgcn_rcpf(d0[n] + d1[n]);
      v.x = (v0.x + v1.x) * inv;
      v.y = (v0.y + v1.y) * inv;
      v.z = (v0.z + v1.z) * inv;
      v.w = (v0.w + v1.w) * inv;
    }
    *(float4*)(&xs[n][c4]) = v;   // rows 60..63 zero-padded
  }
  __syncthreads();

  const int l = tid & 63;
  const int w = tid >> 6;
  const int lg = l >> 4;
  const int lr = l & 15;

  float b1v[8], w2v[8];
#pragma unroll
  for (int nt = 0; nt < 8; ++nt) {
    b1v[nt] = b1[nt * 16 + lr];
    w2v[nt] = w2[nt * 16 + lr];
  }

  f32x4 acc[8];
#pragma unroll
  for (int nt = 0; nt < 8; ++nt) acc[nt] = (f32x4)(0.0f);

  const int row = 16 * w + lr;
#pragma unroll
  for (int kt = 0; kt < 4; ++kt) {
    const int k0 = kt * 32 + 8 * lg;
    float4 a0v = *(const float4*)(&xs[row][k0]);
    float4 a1v = *(const float4*)(&xs[row][k0 + 4]);
    short8 af;
    af[0] = (short)f2bf(a0v.x); af[1] = (short)f2bf(a0v.y);
    af[2] = (short)f2bf(a0v.z); af[3] = (short)f2bf(a0v.w);
    af[4] = (short)f2bf(a1v.x); af[5] = (short)f2bf(a1v.y);
    af[6] = (short)f2bf(a1v.z); af[7] = (short)f2bf(a1v.w);
#pragma unroll
    for (int nt = 0; nt < 8; ++nt) {
      short8 bf = wfrag[(kt * 8 + nt) * 64 + l];
      acc[nt] = __builtin_amdgcn_mfma_f32_16x16x32_bf16(af, bf, acc[nt], 0, 0, 0);
    }
  }

#pragma unroll
  for (int j = 0; j < 4; ++j) {
    float s = 0.f;
#pragma unroll
    for (int nt = 0; nt < 8; ++nt) {
      float h = acc[nt][j] + b1v[nt];
      s += tanh_fast(h) * w2v[nt];
    }
    s += __shfl_xor(s, 1);
    s += __shfl_xor(s, 2);
    s += __shfl_xor(s, 4);
    s += __shfl_xor(s, 8);
    if (lr == 0) score_lds[16 * w + 4 * lg + j] = s;
  }
  __syncthreads();

  // masked softmax over T=60 (no max shift; scores bounded)
  float p = (l < T_) ? __builtin_amdgcn_exp2f(score_lds[l] * 1.4426950408889634f) : 0.f;
  float sm = p;
  sm += __shfl_xor(sm, 32);
  sm += __shfl_xor(sm, 16);
  sm += __shfl_xor(sm, 8);
  sm += __shfl_xor(sm, 4);
  sm += __shfl_xor(sm, 2);
  sm += __shfl_xor(sm, 1);
  float tw = p / sm;
  if (w == 0) {
    tw_lds[l] = tw;
    if (l < T_) out[B_ * D_ + b * T_ + l] = tw;   // tw output
  }
  __syncthreads();

  const int c = tid & 127;
  const int hh = tid >> 7;
  float s = 0.f;
#pragma unroll
  for (int i = 0; i < 30; ++i) {
    int tt = 30 * hh + i;
    s += tw_lds[tt] * xs[tt][c];
  }
  pp[hh][c] = s;
  __syncthreads();
  if (tid < 128) out[(size_t)b * D_ + tid] = pp[0][tid] + pp[1][tid];
}

extern "C" void kernel_launch(void* const* d_in, const int* in_sizes, int n_in,
                              void* d_out, int out_size, void* d_ws, size_t ws_size,
                              hipStream_t stream) {
  const float* x     = (const float*)d_in[0];
  const float* sg_w1 = (const float*)d_in[1];
  const float* sg_b1 = (const float*)d_in[2];
  const float* sg_w2 = (const float*)d_in[3];
  const float* tg_w1 = (const float*)d_in[5];
  const float* tg_b1 = (const float*)d_in[6];
  const float* tg_w2 = (const float*)d_in[7];
  float* out = (float*)d_out;

  unsigned short* wfrag = (unsigned short*)d_ws;            // 64 KB (sg @0, tg @16384)
  float* acc_p = (float*)((char*)d_ws + 65536);             // 512*64*128 f32 = 16.8 MB
  float* den_p = (float*)((char*)d_ws + 65536 + 16777216);  // 512*64 f32

  prep_weights<<<16, 256, 0, stream>>>(sg_w1, tg_w1, wfrag);
  spatial_kernel<<<B_ * 2, 256, 0, stream>>>(
      x, wfrag, sg_b1, sg_w2, acc_p, den_p);
  temporal_kernel<<<B_, 256, 0, stream>>>(
      acc_p, den_p, (const short8*)(wfrag + 16384), tg_b1, tg_w2, out);
}

// Round 11
// 142.477 us; speedup vs baseline: 2.6700x; 1.0200x over previous
//
#include <hip/hip_runtime.h>

#define B_ 256
#define N_ 64
#define T_ 60
#define D_ 128
#define H_ 128

typedef __attribute__((ext_vector_type(8))) short short8;
typedef __attribute__((ext_vector_type(4))) float f32x4;

__device__ __forceinline__ unsigned short f2bf(float f) {
  unsigned int u = __builtin_bit_cast(unsigned int, f);
  u = u + 0x7FFFu + ((u >> 16) & 1u);   // round-to-nearest-even
  return (unsigned short)(u >> 16);
}

__device__ __forceinline__ float tanh_fast(float x) {
  float e = __builtin_amdgcn_exp2f(x * 2.885390081777927f);  // exp(2x)
  return 1.0f - 2.0f * __builtin_amdgcn_rcpf(e + 1.0f);
}

// LDS-only barrier: does not drain vmcnt, so in-flight global prefetch
// loads survive it.
__device__ __forceinline__ void lds_barrier() {
  asm volatile("s_waitcnt lgkmcnt(0)" ::: "memory");
  __builtin_amdgcn_s_barrier();
  asm volatile("" ::: "memory");
}

// Pack W (K=128 x N=128, row-major [k][n]) into bf16 B-fragment order:
// [kt(4)][nt(8)][lane(64)][elem(8)], value = W[kt*32 + 8*(l>>4) + i][nt*16 + (l&15)]
__global__ __launch_bounds__(256) void prep_weights(
    const float* __restrict__ sg_w1, const float* __restrict__ tg_w1,
    unsigned short* __restrict__ wfrag) {
  int tid = blockIdx.x * 256 + threadIdx.x;   // 0..4095
  if (tid >= 2 * 4 * 8 * 64) return;
  int l  = tid & 63;
  int nt = (tid >> 6) & 7;
  int kt = (tid >> 9) & 3;
  int m  = tid >> 11;
  const float* W = m ? tg_w1 : sg_w1;
  int n  = nt * 16 + (l & 15);
  int k0 = kt * 32 + 8 * (l >> 4);
  unsigned short* dst = wfrag + (size_t)tid * 8;
#pragma unroll
  for (int i = 0; i < 8; ++i) dst[i] = f2bf(W[(k0 + i) * H_ + n]);
}

// Block = (b, node-half, t-half): 1024 blocks. Slab = one node's 32-t span
// (16KB contiguous); 32 slabs/block. Online accumulate acc[t][d] += e*x,
// den[t] += e in registers. Halved working set vs R8 -> 3 blocks/CU
// (12 waves, 3 independent load streams; R8 had 8 waves/2 streams).
// (256,2) bound is load-bearing: tighter caps spilled the px dbuf (R9).
__global__ __launch_bounds__(256, 2) void spatial_kernel(
    const float* __restrict__ x,
    const unsigned short* __restrict__ wfrag_g,  // sg_w1 fragments
    const float* __restrict__ b1,
    const float* __restrict__ w2,
    float* __restrict__ acc_p,    // [1024][32][128]
    float* __restrict__ den_p) {  // [1024][32]
  __shared__ __align__(16) char tile[32 * 272];   // bf16 slab, 272B row stride
  __shared__ __align__(16) char wlds[32768];      // 32 B-fragments
  __shared__ float gpart[2][32];

  const int tid = threadIdx.x;
  const int bid = blockIdx.x;
  const int b  = bid >> 2;
  const int nh = (bid >> 1) & 1;
  const int th = bid & 1;

  const int sub = tid >> 5;    // 0..7   (row sub-slot)
  const int cg  = tid & 31;    // 0..31  (col group of 4 floats)

  // base of this block's window: nodes nh*32.., t rows th*32..
  const float* xb = x + (size_t)b * (N_ * T_ * D_)
                      + (size_t)(nh * 32) * (T_ * D_) + (size_t)(th * 32) * D_;

  // per-thread row offsets within a slab; thread owns local rows {8j+sub}.
  // th=1 covers global t=32..63 -> clamp local row to 27 (t=59); padded
  // rows produce finite junk that temporal ignores.
  const int rmax = th ? 27 : 31;
  int roff[4];
#pragma unroll
  for (int j = 0; j < 4; ++j) {
    int r = 8 * j + sub;
    roff[j] = (r > rmax ? rmax : r) * D_ + 4 * cg;
  }

  const int l  = tid & 63;
  const int w  = tid >> 6;
  const int lg = l >> 4;
  const int lr = l & 15;
  const int wr = w >> 1;   // row half of 32: rows [16*wr, 16*wr+16)
  const int wc = w & 1;    // col half: H cols [64*wc, 64*wc+64)

  float b1v[4], w2v[4];
#pragma unroll
  for (int ntl = 0; ntl < 4; ++ntl) {
    b1v[ntl] = b1[wc * 64 + ntl * 16 + lr];
    w2v[ntl] = w2[wc * 64 + ntl * 16 + lr];
  }

  // ---- prologue: W-fragments -> LDS; issue slab-0 loads ----
  float4 wtmp[8];
#pragma unroll
  for (int i = 0; i < 8; ++i)
    wtmp[i] = *(const float4*)(wfrag_g + (size_t)(tid + 256 * i) * 8);

  float4 pxA[4], pxB[4];
#pragma unroll
  for (int j = 0; j < 4; ++j) pxA[j] = *(const float4*)(xb + roff[j]);

#pragma unroll
  for (int i = 0; i < 8; ++i)
    *(float4*)(wlds + (size_t)(tid + 256 * i) * 16) = wtmp[i];
  lds_barrier();

  f32x4 accr[4];
  float denr[4];
#pragma unroll
  for (int j = 0; j < 4; ++j) { accr[j] = (f32x4)(0.0f); denr[j] = 0.0f; }

#define SLAB_BODY(CUR, NXT, S)                                                  \
  {                                                                             \
    /* issue next slab's loads (fly under this slab's compute) */               \
    if ((S) < 31) {                                                             \
      const float* nsb = xb + (size_t)((S) + 1) * (T_ * D_);                    \
      _Pragma("unroll")                                                         \
      for (int j = 0; j < 4; ++j) NXT[j] = *(const float4*)(nsb + roff[j]);     \
    }                                                                           \
    /* A: convert CUR -> bf16 tile (rows 8j+sub) */                             \
    _Pragma("unroll")                                                           \
    for (int j = 0; j < 4; ++j) {                                               \
      const int r = 8 * j + sub;                                                \
      unsigned lo = ((unsigned)f2bf(CUR[j].y) << 16) | f2bf(CUR[j].x);          \
      unsigned hi = ((unsigned)f2bf(CUR[j].w) << 16) | f2bf(CUR[j].z);          \
      *(uint2*)(tile + r * 272 + cg * 8) = make_uint2(lo, hi);                  \
    }                                                                           \
    lds_barrier();                                                              \
    /* B: MFMA h = slab(32 rows) @ W1; wave = (row-half, col-half) */           \
    {                                                                           \
      f32x4 macc[4];                                                            \
      _Pragma("unroll")                                                         \
      for (int ntl = 0; ntl < 4; ++ntl) macc[ntl] = (f32x4)(0.0f);              \
      _Pragma("unroll")                                                         \
      for (int kt = 0; kt < 4; ++kt) {                                          \
        const int row = 16 * wr + lr;                                           \
        short8 af = *(const short8*)(tile + row * 272 + kt * 64 + lg * 16);     \
        _Pragma("unroll")                                                       \
        for (int ntl = 0; ntl < 4; ++ntl) {                                     \
          short8 bf = *(const short8*)(                                         \
              wlds + ((kt * 8 + wc * 4 + ntl) * 64 + l) * 16);                  \
          macc[ntl] = __builtin_amdgcn_mfma_f32_16x16x32_bf16(                  \
              af, bf, macc[ntl], 0, 0, 0);                                      \
        }                                                                       \
      }                                                                         \
      /* gate partials; local row = 16*wr + 4*lg + j */                         \
      _Pragma("unroll")                                                         \
      for (int j = 0; j < 4; ++j) {                                             \
        float sg = 0.f;                                                         \
        _Pragma("unroll")                                                       \
        for (int ntl = 0; ntl < 4; ++ntl) {                                     \
          float h = macc[ntl][j] + b1v[ntl];                                    \
          sg += tanh_fast(h) * w2v[ntl];                                        \
        }                                                                       \
        sg += __shfl_xor(sg, 1);                                                \
        sg += __shfl_xor(sg, 2);                                                \
        sg += __shfl_xor(sg, 4);                                                \
        sg += __shfl_xor(sg, 8);                                                \
        if (lr == 0) gpart[wc][16 * wr + 4 * lg + j] = sg;                      \
      }                                                                         \
    }                                                                           \
    lds_barrier();                                                              \
    /* D: e = exp(gate), online accumulate from CUR registers */                \
    _Pragma("unroll")                                                           \
    for (int j = 0; j < 4; ++j) {                                               \
      const int r = 8 * j + sub;                                                \
      float g = gpart[0][r] + gpart[1][r];                                      \
      float e = __builtin_amdgcn_exp2f(g * 1.4426950408889634f);                \
      accr[j][0] += e * CUR[j].x;                                               \
      accr[j][1] += e * CUR[j].y;                                               \
      accr[j][2] += e * CUR[j].z;                                               \
      accr[j][3] += e * CUR[j].w;                                               \
      denr[j] += e;                                                             \
    }                                                                           \
    lds_barrier();                                                              \
  }

  for (int sp = 0; sp < 16; ++sp) {
    const int s0 = 2 * sp;
    SLAB_BODY(pxA, pxB, s0);
    SLAB_BODY(pxB, pxA, s0 + 1);
  }
#undef SLAB_BODY

  // ---- epilogue: write partial acc / den ----
#pragma unroll
  for (int j = 0; j < 4; ++j) {
    const int r = 8 * j + sub;
    *(f32x4*)(acc_p + ((size_t)bid * 32 + r) * D_ + 4 * cg) = accr[j];
  }
  if (cg == 0) {
#pragma unroll
    for (int j = 0; j < 4; ++j) den_p[bid * 32 + 8 * j + sub] = denr[j];
  }
}

__global__ __launch_bounds__(256) void temporal_kernel(
    const float* __restrict__ acc_p,
    const float* __restrict__ den_p,
    const short8* __restrict__ wfrag,     // fragments of tg_w1
    const float* __restrict__ b1,
    const float* __restrict__ w2,
    float* __restrict__ out) {
  __shared__ float xs[64][132];
  __shared__ float score_lds[64];
  __shared__ float tw_lds[64];
  __shared__ float pp[2][128];

  const int tid = threadIdx.x;
  const int b = blockIdx.x;

  // combine the two node-half partials (bid = b*4 + nh*2 + th) on load
#pragma unroll
  for (int it = 0; it < 8; ++it) {
    int q = it * 256 + tid;
    int n = q >> 5;          // global t
    int c4 = (q & 31) << 2;
    float4 v = {0.f, 0.f, 0.f, 0.f};
    if (n < T_) {
      int thh = n >> 5, tl = n & 31;
      const float* a0 = acc_p + ((size_t)(b * 4 + thh) * 32 + tl) * D_;
      const float* a1 = acc_p + ((size_t)(b * 4 + 2 + thh) * 32 + tl) * D_;
      float4 v0 = *(const float4*)(a0 + c4);
      float4 v1 = *(const float4*)(a1 + c4);
      float inv = __builtin_amdgcn_rcpf(den_p[(b * 4 + thh) * 32 + tl] +
                                        den_p[(b * 4 + 2 + thh) * 32 + tl]);
      v.x = (v0.x + v1.x) * inv;
      v.y = (v0.y + v1.y) * inv;
      v.z = (v0.z + v1.z) * inv;
      v.w = (v0.w + v1.w) * inv;
    }
    *(float4*)(&xs[n][c4]) = v;   // rows 60..63 zero-padded
  }
  __syncthreads();

  const int l = tid & 63;
  const int w = tid >> 6;
  const int lg = l >> 4;
  const int lr = l & 15;

  float b1v[8], w2v[8];
#pragma unroll
  for (int nt = 0; nt < 8; ++nt) {
    b1v[nt] = b1[nt * 16 + lr];
    w2v[nt] = w2[nt * 16 + lr];
  }

  f32x4 acc[8];
#pragma unroll
  for (int nt = 0; nt < 8; ++nt) acc[nt] = (f32x4)(0.0f);

  const int row = 16 * w + lr;
#pragma unroll
  for (int kt = 0; kt < 4; ++kt) {
    const int k0 = kt * 32 + 8 * lg;
    float4 a0v = *(const float4*)(&xs[row][k0]);
    float4 a1v = *(const float4*)(&xs[row][k0 + 4]);
    short8 af;
    af[0] = (short)f2bf(a0v.x); af[1] = (short)f2bf(a0v.y);
    af[2] = (short)f2bf(a0v.z); af[3] = (short)f2bf(a0v.w);
    af[4] = (short)f2bf(a1v.x); af[5] = (short)f2bf(a1v.y);
    af[6] = (short)f2bf(a1v.z); af[7] = (short)f2bf(a1v.w);
#pragma unroll
    for (int nt = 0; nt < 8; ++nt) {
      short8 bf = wfrag[(kt * 8 + nt) * 64 + l];
      acc[nt] = __builtin_amdgcn_mfma_f32_16x16x32_bf16(af, bf, acc[nt], 0, 0, 0);
    }
  }

#pragma unroll
  for (int j = 0; j < 4; ++j) {
    float s = 0.f;
#pragma unroll
    for (int nt = 0; nt < 8; ++nt) {
      float h = acc[nt][j] + b1v[nt];
      s += tanh_fast(h) * w2v[nt];
    }
    s += __shfl_xor(s, 1);
    s += __shfl_xor(s, 2);
    s += __shfl_xor(s, 4);
    s += __shfl_xor(s, 8);
    if (lr == 0) score_lds[16 * w + 4 * lg + j] = s;
  }
  __syncthreads();

  // masked softmax over T=60 (no max shift; scores bounded)
  float p = (l < T_) ? __builtin_amdgcn_exp2f(score_lds[l] * 1.4426950408889634f) : 0.f;
  float sm = p;
  sm += __shfl_xor(sm, 32);
  sm += __shfl_xor(sm, 16);
  sm += __shfl_xor(sm, 8);
  sm += __shfl_xor(sm, 4);
  sm += __shfl_xor(sm, 2);
  sm += __shfl_xor(sm, 1);
  float tw = p / sm;
  if (w == 0) {
    tw_lds[l] = tw;
    if (l < T_) out[B_ * D_ + b * T_ + l] = tw;   // tw output
  }
  __syncthreads();

  const int c = tid & 127;
  const int hh = tid >> 7;
  float s = 0.f;
#pragma unroll
  for (int i = 0; i < 30; ++i) {
    int tt = 30 * hh + i;
    s += tw_lds[tt] * xs[tt][c];
  }
  pp[hh][c] = s;
  __syncthreads();
  if (tid < 128) out[(size_t)b * D_ + tid] = pp[0][tid] + pp[1][tid];
}

extern "C" void kernel_launch(void* const* d_in, const int* in_sizes, int n_in,
                              void* d_out, int out_size, void* d_ws, size_t ws_size,
                              hipStream_t stream) {
  const float* x     = (const float*)d_in[0];
  const float* sg_w1 = (const float*)d_in[1];
  const float* sg_b1 = (const float*)d_in[2];
  const float* sg_w2 = (const float*)d_in[3];
  const float* tg_w1 = (const float*)d_in[5];
  const float* tg_b1 = (const float*)d_in[6];
  const float* tg_w2 = (const float*)d_in[7];
  float* out = (float*)d_out;

  unsigned short* wfrag = (unsigned short*)d_ws;            // 64 KB (sg @0, tg @16384)
  float* acc_p = (float*)((char*)d_ws + 65536);             // 1024*32*128 f32 = 16.8 MB
  float* den_p = (float*)((char*)d_ws + 65536 + 16777216);  // 1024*32 f32

  prep_weights<<<16, 256, 0, stream>>>(sg_w1, tg_w1, wfrag);
  spatial_kernel<<<B_ * 4, 256, 0, stream>>>(
      x, wfrag, sg_b1, sg_w2, acc_p, den_p);
  temporal_kernel<<<B_, 256, 0, stream>>>(
      acc_p, den_p, (const short8*)(wfrag + 16384), tg_b1, tg_w2, out);
}